// Round 1
// baseline (1591.225 us; speedup 1.0000x reference)
//
#include <hip/hip_runtime.h>

#define B_ 32
#define C_ 128
#define HW_ 128
#define CIN_ 64
#define COUT_ 128
#define SPATIAL (HW_ * HW_)  // 16384

// ---------------------------------------------------------------------------
// Kernel 1: per-(b,c) spatial sum, double accumulation (ordering safety).
// One block per (b,c): 4096 blocks x 256 threads, float4 loads.
// ---------------------------------------------------------------------------
__global__ __launch_bounds__(256) void k_chansum(const float* __restrict__ x,
                                                 double* __restrict__ sums) {
    int bc = blockIdx.x;
    const float4* p4 = (const float4*)(x + (size_t)bc * SPATIAL);
    int t = threadIdx.x;
    double s = 0.0;
#pragma unroll
    for (int i = 0; i < 16; ++i) {
        float4 v = p4[t + 256 * i];
        s += (double)v.x + (double)v.y + (double)v.z + (double)v.w;
    }
    // wave(64) butterfly-free down-reduce
#pragma unroll
    for (int off = 32; off > 0; off >>= 1) s += __shfl_down(s, off, 64);
    __shared__ double wsum[4];
    if ((t & 63) == 0) wsum[t >> 6] = s;
    __syncthreads();
    if (t == 0) sums[bc] = wsum[0] + wsum[1] + wsum[2] + wsum[3];
}

// ---------------------------------------------------------------------------
// Kernel 2: stable argsort-by-rank, keep first CIN_ ranks.
// rank = #{j : s[j] < s[c]  ||  (s[j] == s[c] && j < c)}  (stable ascending)
// ---------------------------------------------------------------------------
__global__ __launch_bounds__(128) void k_select(const double* __restrict__ sums,
                                                int* __restrict__ idx) {
    int b = blockIdx.x, c = threadIdx.x;
    __shared__ double s[C_];
    double my = sums[b * C_ + c];
    s[c] = my;
    __syncthreads();
    int rank = 0;
    for (int j = 0; j < C_; ++j) {
        double v = s[j];
        rank += (v < my || (v == my && j < c)) ? 1 : 0;
    }
    if (rank < CIN_) idx[b * CIN_ + rank] = c;
}

// ---------------------------------------------------------------------------
// Kernel 3: direct 3x3 conv over the 64 selected (sorted) channels.
// Block: 256 threads -> tile of 32 co x 8 h x 32 w (32 acc regs/thread).
// Per input channel j: stage 10x34 halo tile into LDS, each thread caches its
// 3x3 window in registers, then 32x9 unrolled FMAs with wave-uniform weights.
// ---------------------------------------------------------------------------
#define HT 8
#define WT 32
#define COT 32

__global__ __launch_bounds__(256) void k_conv(const float* __restrict__ x,
                                              const float* __restrict__ w,
                                              const float* __restrict__ bias,
                                              const int* __restrict__ idx,
                                              float* __restrict__ out) {
    __shared__ float tile[10 * 34];
    __shared__ int sidx[CIN_];

    int b  = blockIdx.z;
    int h0 = blockIdx.y * HT;
    int co0 = (blockIdx.x & 3) * COT;   // co-chunk fastest -> x-tile L2 reuse
    int w0  = (blockIdx.x >> 2) * WT;
    int t = threadIdx.x;

    if (t < CIN_) sidx[t] = idx[b * CIN_ + t];

    float acc[COT];
#pragma unroll
    for (int i = 0; i < COT; ++i) acc[i] = bias[co0 + i];

    int wt = t & 31;   // 0..31 -> w offset
    int ht = t >> 5;   // 0..7  -> h offset

    for (int j = 0; j < CIN_; ++j) {
        __syncthreads();  // protect tile (and sidx on first iter)
        int ci = sidx[j];
        const float* xp = x + (size_t)(b * C_ + ci) * SPATIAL;
        for (int e = t; e < 10 * 34; e += 256) {
            int r = e / 34, c = e - r * 34;
            int gh = h0 + r - 1, gw = w0 + c - 1;
            float v = 0.f;
            if ((unsigned)gh < (unsigned)HW_ && (unsigned)gw < (unsigned)HW_)
                v = xp[gh * HW_ + gw];
            tile[e] = v;
        }
        __syncthreads();

        float wv[9];
#pragma unroll
        for (int dh = 0; dh < 3; ++dh)
#pragma unroll
            for (int dw = 0; dw < 3; ++dw)
                wv[dh * 3 + dw] = tile[(ht + dh) * 34 + wt + dw];

        const float* wp = w + (size_t)co0 * (CIN_ * 9) + j * 9;
#pragma unroll
        for (int co = 0; co < COT; ++co) {
            const float* wc = wp + co * (CIN_ * 9);
#pragma unroll
            for (int k = 0; k < 9; ++k)
                acc[co] = fmaf(wc[k], wv[k], acc[co]);
        }
    }

    size_t obase = ((size_t)(b * COUT_ + co0) * HW_ + (size_t)(h0 + ht)) * HW_ + w0 + wt;
#pragma unroll
    for (int co = 0; co < COT; ++co)
        out[obase + (size_t)co * SPATIAL] = acc[co];
}

// ---------------------------------------------------------------------------
extern "C" void kernel_launch(void* const* d_in, const int* in_sizes, int n_in,
                              void* d_out, int out_size, void* d_ws, size_t ws_size,
                              hipStream_t stream) {
    const float* x    = (const float*)d_in[0];
    const float* w    = (const float*)d_in[1];
    const float* bias = (const float*)d_in[2];
    float* out = (float*)d_out;

    double* sums = (double*)d_ws;                                  // 4096 * 8 B
    int* idx = (int*)((char*)d_ws + (size_t)B_ * C_ * sizeof(double));  // 2048 * 4 B

    k_chansum<<<B_ * C_, 256, 0, stream>>>(x, sums);
    k_select<<<B_, 128, 0, stream>>>(sums, idx);

    dim3 grid(16 /* 4 w-tiles * 4 co-chunks */, 16 /* h-tiles */, B_);
    k_conv<<<grid, 256, 0, stream>>>(x, w, bias, idx, out);
}